// Round 1
// baseline (98.896 us; speedup 1.0000x reference)
//
#include <hip/hip_runtime.h>
#include <math.h>

#define EPS 1e-4f

__device__ __forceinline__ float wave_sum(float v) {
    for (int m = 1; m < 64; m <<= 1)
        v += __shfl_xor(v, m, 64);
    return v;
}

// Kernel A: Y[tensor][b][t][k] = (w0*x[2k] + w1*x[2k+1]) / (dot(x,x)+EPS)
// One wave per (tensor,b,t); lane k holds x[2k],x[2k+1].
__global__ __launch_bounds__(256) void prep_y(
    const int* __restrict__ q, const int* __restrict__ a,
    const float* __restrict__ emb, const float* __restrict__ cw,
    float* __restrict__ Y)
{
    int wid  = blockIdx.x * 4 + (threadIdx.x >> 6);   // [0,2048)
    int lane = threadIdx.x & 63;
    int tensor = wid >> 10;
    int b      = (wid >> 6) & 15;
    int t      = wid & 63;
    const int* toks = tensor ? a : q;
    int tok = toks[b * 64 + t];
    float2 xv = ((const float2*)(emb + (size_t)tok * 128))[lane];
    float s = wave_sum(xv.x * xv.x + xv.y * xv.y) + EPS;
    float w0 = cw[0], w1 = cw[1];
    Y[(size_t)wid * 64 + lane] = (w0 * xv.x + w1 * xv.y) / s;
}

// Kernel B: the 2-layer scan + running max. One wave per (tensor,b,j).
// Lane l owns rows l (lo) and l+64 (hi) of the 128-row state.
// hn[l]    = tanh(w0*x[2l] + w1*x[2l+1] + b)          (input rows)
// hn[l+64] = tanh(w0*h[2l] + w1*h[2l+1] + b)          (state rows)
// Layer-1 input rows: w0*d[2l][j]+w1*d[2l+1][j] = Y[l]*x[j].
__global__ __launch_bounds__(256) void rnn_max(
    const int* __restrict__ q, const int* __restrict__ a,
    const float* __restrict__ emb, const float* __restrict__ cw,
    const float* __restrict__ cb, const float* __restrict__ Y,
    float* __restrict__ mm)
{
    int wid  = blockIdx.x * 4 + (threadIdx.x >> 6);   // [0,4096)
    int lane = threadIdx.x & 63;
    int tensor = wid >> 11;
    int b      = (wid >> 7) & 15;
    int j      = wid & 127;
    const int* toks = (tensor ? a : q) + b * 64;
    const float* Yw = Y + (size_t)(tensor * 16 + b) * 4096;
    float w10 = cw[0], w11 = cw[1], b1 = cb[0];
    float w20 = cw[2], w21 = cw[3], b2 = cb[1];
    int  s0 = (2 * lane) & 63;
    int  s1 = (2 * lane + 1) & 63;
    bool losel = lane < 32;                 // row 2l (and 2l+1) < 64 ?

    float h1lo = 0.f, h1hi = 0.f, h2lo = 0.f, h2hi = 0.f;
    float mlo = -1e30f, mhi = -1e30f;

    for (int t = 0; t < 64; ++t) {
        int tok = toks[t];
        float xj = emb[(size_t)tok * 128 + j];
        float yv = Yw[t * 64 + lane];
        // ---- layer 1 ----
        float a0l = __shfl(h1lo, s0, 64), a0h = __shfl(h1hi, s0, 64);
        float a1l = __shfl(h1lo, s1, 64), a1h = __shfl(h1hi, s1, 64);
        float a0 = losel ? a0l : a0h;
        float a1 = losel ? a1l : a1h;
        float n1lo = tanhf(fmaf(yv, xj, b1));
        float n1hi = tanhf(fmaf(w10, a0, fmaf(w11, a1, b1)));
        // ---- layer 2 (consumes layer-1 output of the SAME t) ----
        float c0l = __shfl(n1lo, s0, 64), c0h = __shfl(n1hi, s0, 64);
        float c1l = __shfl(n1lo, s1, 64), c1h = __shfl(n1hi, s1, 64);
        float c0 = losel ? c0l : c0h;
        float c1 = losel ? c1l : c1h;
        float e0l = __shfl(h2lo, s0, 64), e0h = __shfl(h2hi, s0, 64);
        float e1l = __shfl(h2lo, s1, 64), e1h = __shfl(h2hi, s1, 64);
        float e0 = losel ? e0l : e0h;
        float e1 = losel ? e1l : e1h;
        float n2lo = tanhf(fmaf(w20, c0, fmaf(w21, c1, b2)));
        float n2hi = tanhf(fmaf(w20, e0, fmaf(w21, e1, b2)));
        h1lo = n1lo; h1hi = n1hi; h2lo = n2lo; h2hi = n2hi;
        mlo = fmaxf(mlo, n2lo); mhi = fmaxf(mhi, n2hi);
    }
    // mm layout: [tensor][b][row*128 + col] — matches reshape(B,L,D*D) flatten
    float* o = mm + (size_t)(tensor * 16 + b) * 16384;
    o[lane * 128 + j]        = mlo;
    o[(lane + 64) * 128 + j] = mhi;
}

// Kernel C: score[b][c] = sum_k qa[b][k]*lin_w[c][k] + lin_b[c]; log_softmax.
__global__ __launch_bounds__(256) void lin_lsm(
    const float* __restrict__ mm, const float* __restrict__ lw,
    const float* __restrict__ lb, float* __restrict__ out)
{
    int b = blockIdx.x;
    int tid = threadIdx.x;
    const float* qm = mm + (size_t)b * 16384;
    const float* am = mm + (size_t)(16 + b) * 16384;
    float acc0 = 0.f, acc1 = 0.f;
    for (int k = tid; k < 32768; k += 256) {
        float v = (k < 16384) ? qm[k] : am[k - 16384];
        acc0 = fmaf(v, lw[k], acc0);
        acc1 = fmaf(v, lw[32768 + k], acc1);
    }
    acc0 = wave_sum(acc0);
    acc1 = wave_sum(acc1);
    __shared__ float red[8];
    int w = tid >> 6, lane = tid & 63;
    if (lane == 0) { red[w * 2] = acc0; red[w * 2 + 1] = acc1; }
    __syncthreads();
    if (tid == 0) {
        float s0 = red[0] + red[2] + red[4] + red[6] + lb[0];
        float s1 = red[1] + red[3] + red[5] + red[7] + lb[1];
        float m = fmaxf(s0, s1);
        float lse = m + logf(expf(s0 - m) + expf(s1 - m));
        out[b * 2 + 0] = s0 - lse;
        out[b * 2 + 1] = s1 - lse;
    }
}

extern "C" void kernel_launch(void* const* d_in, const int* in_sizes, int n_in,
                              void* d_out, int out_size, void* d_ws, size_t ws_size,
                              hipStream_t stream) {
    const int*   q   = (const int*)d_in[0];
    const int*   a   = (const int*)d_in[1];
    const float* emb = (const float*)d_in[2];
    const float* cw  = (const float*)d_in[3];
    const float* cb  = (const float*)d_in[4];
    const float* lw  = (const float*)d_in[5];
    const float* lb  = (const float*)d_in[6];
    float* out = (float*)d_out;

    float* Y  = (float*)d_ws;              // 2*16*64*64   = 131072 floats (512 KB)
    float* mm = (float*)d_ws + 131072;     // 2*16*128*128 = 524288 floats (2 MB)

    prep_y <<<512,  256, 0, stream>>>(q, a, emb, cw, Y);
    rnn_max<<<1024, 256, 0, stream>>>(q, a, emb, cw, cb, Y, mm);
    lin_lsm<<<16,   256, 0, stream>>>(mm, lw, lb, out);
}

// Round 2
// 43.979 us; speedup vs baseline: 2.2487x; 2.2487x over previous
//
#include <hip/hip_runtime.h>
#include <math.h>

#define EPS 1e-4f

__device__ __forceinline__ float wave_sum(float v) {
    for (int m = 1; m < 64; m <<= 1)
        v += __shfl_xor(v, m, 64);
    return v;
}

// tanh(x) = 1 - 2/(exp(2x)+1). exp via v_exp_f32, div via v_rcp_f32 (~1ulp).
// Large |x| saturates correctly through inf/0 arithmetic.
__device__ __forceinline__ float fast_tanh(float x) {
    float e = __expf(2.0f * x);
    return fmaf(-2.0f, __builtin_amdgcn_rcpf(e + 1.0f), 1.0f);
}

// Kernel A: Y[tensor][b][t][k] = (w0*x[2k] + w1*x[2k+1]) / (dot(x,x)+EPS)
__global__ __launch_bounds__(256) void prep_y(
    const int* __restrict__ q, const int* __restrict__ a,
    const float* __restrict__ emb, const float* __restrict__ cw,
    float* __restrict__ Y)
{
    int wid  = blockIdx.x * 4 + (threadIdx.x >> 6);   // [0,2048)
    int lane = threadIdx.x & 63;
    int tensor = wid >> 10;
    int b      = (wid >> 6) & 15;
    int t      = wid & 63;
    const int* toks = tensor ? a : q;
    int tok = toks[b * 64 + t];
    float2 xv = ((const float2*)(emb + (size_t)tok * 128))[lane];
    float s = wave_sum(xv.x * xv.x + xv.y * xv.y) + EPS;
    float w0 = cw[0], w1 = cw[1];
    Y[(size_t)wid * 64 + lane] = (w0 * xv.x + w1 * xv.y) / s;
}

// Kernel B: 2-layer strided-conv RNN scan + running max.
// One wave per (tensor,b,j). Lane l owns rows l and l+64.
// State lives in wave-private LDS, interleaved: H[k] = (h1[k], h2[k]).
// new row k<64  : tanh(w0*x[2k] + w1*x[2k+1] + b)  [layer1: = tanh(y[k]*x[j]+b1)]
// new row k>=64 : tanh(w0*h[2(k-64)] + w1*h[2(k-64)+1] + b)
__global__ __launch_bounds__(256) void rnn_max(
    const int* __restrict__ q, const int* __restrict__ a,
    const float* __restrict__ emb, const float* __restrict__ cw,
    const float* __restrict__ cb, const float* __restrict__ Y,
    float* __restrict__ mm)
{
    __shared__ __align__(16) float2 h12[4][128];
    int w    = threadIdx.x >> 6;
    int lane = threadIdx.x & 63;
    int wid  = blockIdx.x * 4 + w;                    // [0,4096)
    int tensor = wid >> 11;
    int b      = (wid >> 7) & 15;
    int j      = wid & 127;
    const int*   toks = (tensor ? a : q) + b * 64;
    const float* Yw   = Y + (size_t)(tensor * 16 + b) * 4096 + lane;
    const float* embj = emb + j;
    float w10 = cw[0], w11 = cw[1], b1 = cb[0];
    float w20 = cw[2], w21 = cw[3], b2 = cb[1];

    float2* H  = h12[w];
    float2* Hr = H + 2 * lane;      // read base: rows 2l, 2l+1
    H[lane]      = make_float2(0.f, 0.f);
    H[lane + 64] = make_float2(0.f, 0.f);

    float mlo = -1e30f, mhi = -1e30f;

    // prefetch t=0
    int   tok = toks[0];
    float xj  = embj[(size_t)tok * 128];
    float yv  = Yw[0];

    for (int t = 0; t < 64; ++t) {
        // ---- prefetch t+1 (issued before the fenced body) ----
        int   tn   = (t < 63) ? t + 1 : 63;
        int   tokn = toks[tn];
        float xjn  = embj[(size_t)tokn * 128];
        float yvn  = Yw[tn * 64];

        // old state: h1[2l], h2[2l], h1[2l+1], h2[2l+1] in one ds_read_b128
        float4 old = *(const float4*)Hr;
        asm volatile("" ::: "memory");   // reads of old state precede writes

        // ---- layer 1 ----
        float n1lo = fast_tanh(fmaf(yv, xj, b1));
        float n1hi = fast_tanh(fmaf(w10, old.x, fmaf(w11, old.z, b1)));
        H[lane].x      = n1lo;
        H[lane + 64].x = n1hi;

        // ---- layer 2 (reads NEW layer-1 rows 2l, 2l+1) ----
        float pa = Hr[0].x;
        float pb = Hr[1].x;
        float n2lo = fast_tanh(fmaf(w20, pa,    fmaf(w21, pb,    b2)));
        float n2hi = fast_tanh(fmaf(w20, old.y, fmaf(w21, old.w, b2)));
        asm volatile("" ::: "memory");   // n1 read-back precedes h2 writes
        H[lane].y      = n2lo;
        H[lane + 64].y = n2hi;

        mlo = fmaxf(mlo, n2lo);
        mhi = fmaxf(mhi, n2hi);

        xj = xjn; yv = yvn; tok = tokn;
    }

    float* o = mm + (size_t)(tensor * 16 + b) * 16384 + j;
    o[lane * 128]        = mlo;
    o[(lane + 64) * 128] = mhi;
}

// Kernel C1: partial dot-products. Block (b, slice s): k in [s*2048,(s+1)*2048).
__global__ __launch_bounds__(256) void lin_partial(
    const float* __restrict__ mm, const float* __restrict__ lw,
    float* __restrict__ part)
{
    int b   = blockIdx.x >> 4;
    int s   = blockIdx.x & 15;
    int tid = threadIdx.x;
    int k0  = s * 2048;
    const float* src = (k0 < 16384) ? (mm + (size_t)b * 16384 + k0)
                                    : (mm + (size_t)(16 + b) * 16384 + (k0 - 16384));
    const float* l0 = lw + k0;
    const float* l1 = lw + 32768 + k0;
    float acc0 = 0.f, acc1 = 0.f;
    for (int kk = tid; kk < 2048; kk += 256) {
        float v = src[kk];
        acc0 = fmaf(v, l0[kk], acc0);
        acc1 = fmaf(v, l1[kk], acc1);
    }
    acc0 = wave_sum(acc0);
    acc1 = wave_sum(acc1);
    __shared__ float red[8];
    int wv = tid >> 6, lane = tid & 63;
    if (lane == 0) { red[wv * 2] = acc0; red[wv * 2 + 1] = acc1; }
    __syncthreads();
    if (tid == 0) {
        part[blockIdx.x * 2 + 0] = red[0] + red[2] + red[4] + red[6];
        part[blockIdx.x * 2 + 1] = red[1] + red[3] + red[5] + red[7];
    }
}

// Kernel C2: final reduce + bias + log_softmax. 32 active threads.
__global__ __launch_bounds__(64) void lin_final(
    const float* __restrict__ part, const float* __restrict__ lb,
    float* __restrict__ out)
{
    int tid = threadIdx.x;
    int b = tid >> 1, c = tid & 1;
    float sum = 0.f;
    if (tid < 32) {
        sum = lb[c];
        for (int s = 0; s < 16; ++s)
            sum += part[(b * 16 + s) * 2 + c];
    }
    float other = __shfl_xor(sum, 1, 64);
    if (tid < 32) {
        float m   = fmaxf(sum, other);
        float lse = m + logf(expf(sum - m) + expf(other - m));
        out[tid]  = sum - lse;
    }
}

extern "C" void kernel_launch(void* const* d_in, const int* in_sizes, int n_in,
                              void* d_out, int out_size, void* d_ws, size_t ws_size,
                              hipStream_t stream) {
    const int*   q   = (const int*)d_in[0];
    const int*   a   = (const int*)d_in[1];
    const float* emb = (const float*)d_in[2];
    const float* cw  = (const float*)d_in[3];
    const float* cb  = (const float*)d_in[4];
    const float* lw  = (const float*)d_in[5];
    const float* lb  = (const float*)d_in[6];
    float* out = (float*)d_out;

    float* Y    = (float*)d_ws;                       // 131072 floats
    float* mm   = (float*)d_ws + 131072;              // 524288 floats
    float* part = (float*)d_ws + 131072 + 524288;     // 512 floats

    prep_y     <<<512,  256, 0, stream>>>(q, a, emb, cw, Y);
    rnn_max    <<<1024, 256, 0, stream>>>(q, a, emb, cw, cb, Y, mm);
    lin_partial<<<256,  256, 0, stream>>>(mm, lw, part);
    lin_final  <<<1,    64,  0, stream>>>(part, lb, out);
}